// Round 1
// baseline (163.408 us; speedup 1.0000x reference)
//
#include <hip/hip_runtime.h>
#include <hip/hip_bf16.h>

typedef __bf16 bf16x8 __attribute__((ext_vector_type(8)));
typedef float f32x4 __attribute__((ext_vector_type(4)));

#define FEAT 2048
#define HID  1024
#define AD   512
#define NB   128
#define NP   196
#define MROWS (NB * NP)      // 25088
#define BM 128
#define BK 64
#define NSTEP (FEAT / BK)    // 32

// ---------------- pack We (fp32 [512][2048]) -> bf16 MFMA-fragment order ----------------
// For 16x16x32 MFMA, B-operand lane l needs We[nt*16 + (l&15)][kt*32 + (l>>4)*8 + e].
// Packed: off = ((kt*32 + nt)*64 + l)*8 + e  -> a wave's fragment load is 1KB contiguous.
__global__ __launch_bounds__(256) void pack_we_k(const float* __restrict__ We,
                                                 __bf16* __restrict__ Bp) {
    int t = blockIdx.x * 256 + threadIdx.x;   // 131072 threads, 8 elems each
    int a  = t >> 8;
    int f0 = (t & 255) << 3;
    const float4* src = reinterpret_cast<const float4*>(We + ((size_t)a << 11) + f0);
    float4 x0 = src[0], x1 = src[1];
    int nt = a >> 4, r = a & 15;
    int kt = f0 >> 5, g = (f0 >> 3) & 3;
    size_t off = (((size_t)(kt * 32 + nt) * 64) + (r + (g << 4))) << 3;
    union { __bf16 h[8]; bf16x8 v; } u;
    u.h[0] = (__bf16)x0.x; u.h[1] = (__bf16)x0.y; u.h[2] = (__bf16)x0.z; u.h[3] = (__bf16)x0.w;
    u.h[4] = (__bf16)x1.x; u.h[5] = (__bf16)x1.y; u.h[6] = (__bf16)x1.z; u.h[7] = (__bf16)x1.w;
    *reinterpret_cast<bf16x8*>(Bp + off) = u.v;
}

// ---------------- dec[b][n] = hidden[b]·Wd[n] + bd[n] + be[n]  (fp32, exact) ------------
__global__ __launch_bounds__(256) void dec_k(const float* __restrict__ hidden,
                                             const float* __restrict__ Wd,
                                             const float* __restrict__ bd,
                                             const float* __restrict__ be,
                                             float* __restrict__ decb) {
    __shared__ float w[8][1028];              // +4 pad: n' hits distinct bank quads
    const int tid = threadIdx.x;
    const int n0 = blockIdx.x << 3;           // 64 blocks x 8 n-rows
    const float4* wsrc = reinterpret_cast<const float4*>(Wd + ((size_t)n0 << 10));
    #pragma unroll
    for (int i = 0; i < 8; ++i)
        *reinterpret_cast<float4*>(&w[i][tid << 2]) = wsrc[(i << 8) + tid];
    __syncthreads();
    const int nl = tid & 7, b0 = tid >> 3;    // 8 n x 32 b-groups
    float acc[4] = {0.f, 0.f, 0.f, 0.f};
    const float4* wp = reinterpret_cast<const float4*>(&w[nl][0]);
    #pragma unroll 2
    for (int k4 = 0; k4 < 256; ++k4) {
        float4 wv = wp[k4];
        #pragma unroll
        for (int i = 0; i < 4; ++i) {
            const float4 h = reinterpret_cast<const float4*>(
                hidden + ((size_t)(b0 + (i << 5)) << 10))[k4];
            acc[i] = fmaf(wv.x, h.x, acc[i]);
            acc[i] = fmaf(wv.y, h.y, acc[i]);
            acc[i] = fmaf(wv.z, h.z, acc[i]);
            acc[i] = fmaf(wv.w, h.w, acc[i]);
        }
    }
    const float bias = bd[n0 + nl] + be[n0 + nl];
    #pragma unroll
    for (int i = 0; i < 4; ++i)
        decb[(size_t)(b0 + (i << 5)) * AD + n0 + nl] = acc[i] + bias;
}

// ---------------- main fused kernel: enc GEMM + tanh + Wf-dot -> scores ----------------
__device__ __forceinline__ void store16(char* d0, char* d1,
                                        float4 a, float4 b, float4 c, float4 d) {
    union { __bf16 h[8]; bf16x8 v; } u0, u1;
    u0.h[0]=(__bf16)a.x; u0.h[1]=(__bf16)a.y; u0.h[2]=(__bf16)a.z; u0.h[3]=(__bf16)a.w;
    u0.h[4]=(__bf16)b.x; u0.h[5]=(__bf16)b.y; u0.h[6]=(__bf16)b.z; u0.h[7]=(__bf16)b.w;
    u1.h[0]=(__bf16)c.x; u1.h[1]=(__bf16)c.y; u1.h[2]=(__bf16)c.z; u1.h[3]=(__bf16)c.w;
    u1.h[4]=(__bf16)d.x; u1.h[5]=(__bf16)d.y; u1.h[6]=(__bf16)d.z; u1.h[7]=(__bf16)d.w;
    *reinterpret_cast<bf16x8*>(d0) = u0.v;
    *reinterpret_cast<bf16x8*>(d1) = u1.v;
}

__device__ __forceinline__ void do_step(const char* buf, const __bf16* __restrict__ bs,
                                        int rc0, int rc1, int lr, f32x4 acc[8][4]) {
    #pragma unroll
    for (int kt2 = 0; kt2 < 2; ++kt2) {
        const __bf16* bk = bs + kt2 * 16384;   // kt stride = 32*512 elems
        bf16x8 b0 = *reinterpret_cast<const bf16x8*>(bk);
        bf16x8 b1 = *reinterpret_cast<const bf16x8*>(bk + 512);
        bf16x8 b2 = *reinterpret_cast<const bf16x8*>(bk + 1024);
        bf16x8 b3 = *reinterpret_cast<const bf16x8*>(bk + 1536);
        const int rc = kt2 ? rc1 : rc0;
        #pragma unroll
        for (int mt = 0; mt < 8; ++mt) {
            bf16x8 a = *reinterpret_cast<const bf16x8*>(buf + (mt * 16 + lr) * 128 + rc);
            acc[mt][0] = __builtin_amdgcn_mfma_f32_16x16x32_bf16(a, b0, acc[mt][0], 0, 0, 0);
            acc[mt][1] = __builtin_amdgcn_mfma_f32_16x16x32_bf16(a, b1, acc[mt][1], 0, 0, 0);
            acc[mt][2] = __builtin_amdgcn_mfma_f32_16x16x32_bf16(a, b2, acc[mt][2], 0, 0, 0);
            acc[mt][3] = __builtin_amdgcn_mfma_f32_16x16x32_bf16(a, b3, acc[mt][3], 0, 0, 0);
        }
    }
}

__global__ __launch_bounds__(512, 2) void enc_score_k(
        const float* __restrict__ X, const __bf16* __restrict__ Bp,
        const float* __restrict__ decb, const float* __restrict__ Wf,
        float* __restrict__ scores) {
    __shared__ char ldsA0[BM * BK * 2];       // 16 KB
    __shared__ char ldsA1[BM * BK * 2];       // 16 KB
    __shared__ float swave[8][BM];
    const int tid  = threadIdx.x;
    const int wave = tid >> 6, lane = tid & 63;
    const int lr = lane & 15, lg = lane >> 4;
    const int row0 = blockIdx.x * BM;

    // acc init = dec[b][n]  (C/D layout: col=lane&15, row=(lane>>4)*4+j)
    f32x4 acc[8][4];
    #pragma unroll
    for (int mt = 0; mt < 8; ++mt) {
        #pragma unroll
        for (int j = 0; j < 4; ++j) {
            const int row = mt * 16 + lg * 4 + j;
            const int b = (unsigned)(row0 + row) / 196u;
            const float* dp = decb + (size_t)b * AD + wave * 64 + lr;
            #pragma unroll
            for (int nt = 0; nt < 4; ++nt) acc[mt][nt][j] = dp[nt * 16];
        }
    }

    // A staging: thread -> (row = tid>>2, 16-elem chunk q = tid&3), XOR-swizzled LDS
    const int srow = tid >> 2, sq = tid & 3;
    const float* gA = X + (size_t)(row0 + srow) * FEAT + sq * 16;
    const int swz = (srow & 7) << 4;
    char* wp0a = ldsA0 + srow * 128 + ((sq * 32) ^ swz);
    char* wp0b = ldsA0 + srow * 128 + ((sq * 32 + 16) ^ swz);
    char* wp1a = ldsA1 + srow * 128 + ((sq * 32) ^ swz);
    char* wp1b = ldsA1 + srow * 128 + ((sq * 32 + 16) ^ swz);

    const int rswz = (lr & 7) << 4;
    const int rc0 = (lg * 16) ^ rswz;
    const int rc1 = (64 + lg * 16) ^ rswz;
    const __bf16* bbase = Bp + wave * 2048 + lane * 8;

    float4 rA0, rA1, rA2, rA3, rB0, rB1, rB2, rB3;
    {   const float4* g = reinterpret_cast<const float4*>(gA);
        rA0 = g[0]; rA1 = g[1]; rA2 = g[2]; rA3 = g[3]; }
    store16(wp0a, wp0b, rA0, rA1, rA2, rA3);
    {   const float4* g = reinterpret_cast<const float4*>(gA + 64);
        rB0 = g[0]; rB1 = g[1]; rB2 = g[2]; rB3 = g[3]; }

    for (int s = 0; s < NSTEP; s += 2) {
        const bool more = (s + 2 < NSTEP);
        __syncthreads();
        if (more) {   // prefetch step s+2 (overlaps compute on buf0)
            const float4* g = reinterpret_cast<const float4*>(gA + (size_t)(s + 2) * BK);
            rA0 = g[0]; rA1 = g[1]; rA2 = g[2]; rA3 = g[3];
        }
        do_step(ldsA0, bbase + (size_t)s * 32768, rc0, rc1, lr, acc);
        store16(wp1a, wp1b, rB0, rB1, rB2, rB3);          // stage step s+1
        __syncthreads();
        if (more) {   // prefetch step s+3
            const float4* g = reinterpret_cast<const float4*>(gA + (size_t)(s + 3) * BK);
            rB0 = g[0]; rB1 = g[1]; rB2 = g[2]; rB3 = g[3];
        }
        do_step(ldsA1, bbase + (size_t)(s + 1) * 32768, rc0, rc1, lr, acc);
        if (more) store16(wp0a, wp0b, rA0, rA1, rA2, rA3); // stage step s+2
    }

    // epilogue: score[row] += sum_n tanh(acc)*Wf[n]; reduce 16 lanes, then 8 waves
    float wf[4];
    #pragma unroll
    for (int nt = 0; nt < 4; ++nt) wf[nt] = Wf[wave * 64 + nt * 16 + lr];
    #pragma unroll
    for (int mt = 0; mt < 8; ++mt) {
        #pragma unroll
        for (int j = 0; j < 4; ++j) {
            float s = 0.f;
            #pragma unroll
            for (int nt = 0; nt < 4; ++nt) {
                float x = acc[mt][nt][j];
                float e = __expf(2.0f * x);
                float t = 1.0f - 2.0f / (e + 1.0f);   // tanh, no-NaN at +/-inf
                s = fmaf(t, wf[nt], s);
            }
            s += __shfl_xor(s, 1); s += __shfl_xor(s, 2);
            s += __shfl_xor(s, 4); s += __shfl_xor(s, 8);
            if (lr == 0) swave[wave][mt * 16 + lg * 4 + j] = s;
        }
    }
    __syncthreads();
    if (tid < BM) {
        float s = 0.f;
        #pragma unroll
        for (int w = 0; w < 8; ++w) s += swave[w][tid];
        scores[row0 + tid] = s;   // bf[0] omitted: softmax-invariant
    }
}

// ---------------- softmax over P=196 per batch row ----------------
__global__ __launch_bounds__(64) void softmax_k(const float* __restrict__ scores,
                                                float* __restrict__ alpha) {
    const int b = blockIdx.x, lane = threadIdx.x;
    float v[4], e[4];
    float m = -3.0e38f;
    #pragma unroll
    for (int i = 0; i < 4; ++i) {
        int p = i * 64 + lane;
        v[i] = (p < NP) ? scores[b * NP + p] : -3.0e38f;
        m = fmaxf(m, v[i]);
    }
    #pragma unroll
    for (int o = 1; o < 64; o <<= 1) m = fmaxf(m, __shfl_xor(m, o));
    float s = 0.f;
    #pragma unroll
    for (int i = 0; i < 4; ++i) {
        int p = i * 64 + lane;
        e[i] = (p < NP) ? __expf(v[i] - m) : 0.f;
        s += e[i];
    }
    #pragma unroll
    for (int o = 1; o < 64; o <<= 1) s += __shfl_xor(s, o);
    const float inv = 1.0f / s;
    #pragma unroll
    for (int i = 0; i < 4; ++i) {
        int p = i * 64 + lane;
        if (p < NP) alpha[b * NP + p] = e[i] * inv;
    }
}

// ---------------- context[b][f] = sum_p alpha[b][p] * X[b][p][f]  (fp32) ----------------
__global__ __launch_bounds__(128) void context_k(const float* __restrict__ X,
                                                 const float* __restrict__ alpha,
                                                 float* __restrict__ ctx) {
    __shared__ float al[NP];
    const int bid = blockIdx.x;
    const int b = 127 - (bid >> 2);       // reverse order: ride L3 residue from GEMM pass
    const int chunk = bid & 3;
    const int tid = threadIdx.x;
    for (int i = tid; i < NP; i += 128) al[i] = alpha[b * NP + i];
    __syncthreads();
    const float4* Xp = reinterpret_cast<const float4*>(X + (size_t)b * NP * FEAT)
                       + chunk * 128 + tid;
    float4 a0 = {0,0,0,0}, a1 = {0,0,0,0};
    #pragma unroll 4
    for (int p = 0; p < NP; p += 2) {
        const float w0 = al[p], w1 = al[p + 1];
        const float4 x0 = Xp[(size_t)p * 512];
        const float4 x1 = Xp[(size_t)(p + 1) * 512];
        a0.x = fmaf(w0, x0.x, a0.x); a0.y = fmaf(w0, x0.y, a0.y);
        a0.z = fmaf(w0, x0.z, a0.z); a0.w = fmaf(w0, x0.w, a0.w);
        a1.x = fmaf(w1, x1.x, a1.x); a1.y = fmaf(w1, x1.y, a1.y);
        a1.z = fmaf(w1, x1.z, a1.z); a1.w = fmaf(w1, x1.w, a1.w);
    }
    float4 r; r.x = a0.x + a1.x; r.y = a0.y + a1.y; r.z = a0.z + a1.z; r.w = a0.w + a1.w;
    *reinterpret_cast<float4*>(ctx + (size_t)b * FEAT + chunk * 512 + tid * 4) = r;
}

extern "C" void kernel_launch(void* const* d_in, const int* in_sizes, int n_in,
                              void* d_out, int out_size, void* d_ws, size_t ws_size,
                              hipStream_t stream) {
    const float* enc    = (const float*)d_in[0];
    const float* hidden = (const float*)d_in[1];
    const float* We     = (const float*)d_in[2];
    const float* be     = (const float*)d_in[3];
    const float* Wd     = (const float*)d_in[4];
    const float* bd     = (const float*)d_in[5];
    const float* Wf     = (const float*)d_in[6];
    // d_in[7] = bf: additive constant to all scores -> softmax-invariant, unused.

    float* out   = (float*)d_out;
    float* ctx   = out;                  // [128*2048]
    float* alpha = out + NB * FEAT;      // [128*196]

    char* ws = (char*)d_ws;
    __bf16* Bp    = (__bf16*)ws;                                   // 2 MB packed We
    float*  decb  = (float*)(ws + (2u << 20));                     // 256 KB
    float*  score = (float*)(ws + (2u << 20) + (256u << 10));      // 100 KB

    pack_we_k  <<<dim3(512), dim3(256), 0, stream>>>(We, Bp);
    dec_k      <<<dim3(64),  dim3(256), 0, stream>>>(hidden, Wd, bd, be, decb);
    enc_score_k<<<dim3(MROWS / BM), dim3(512), 0, stream>>>(enc, Bp, decb, Wf, score);
    softmax_k  <<<dim3(NB),  dim3(64),  0, stream>>>(score, alpha);
    context_k  <<<dim3(512), dim3(128), 0, stream>>>(enc, alpha, ctx);
}